// Round 1
// baseline (710.220 us; speedup 1.0000x reference)
//
#include <hip/hip_runtime.h>
#include <math.h>

// Problem constants (B,N,C fixed by the reference setup).
#define BB 16
#define NN 2048
#define CC 64
#define ROWS 6                       // pruned rows per block in argmax kernel
#define E_CONST 2.71828182845904523536f
#define NEG100  -100.0f

// ---------------------------------------------------------------------------
// K1: row-normalize x -> xn.  One wave (64 lanes) per row, lane = channel.
// ---------------------------------------------------------------------------
__global__ __launch_bounds__(256) void k_normalize(const float* __restrict__ x,
                                                   float* __restrict__ xn) {
    int row  = blockIdx.x * 4 + (threadIdx.x >> 6);   // 4 waves/block
    int lane = threadIdx.x & 63;
    float v  = x[row * CC + lane];
    float sq = v * v;
#pragma unroll
    for (int off = 32; off > 0; off >>= 1)
        sq += __shfl_xor(sq, off, 64);
    float norm = sqrtf(sq) + 1e-6f;
    xn[row * CC + lane] = v / norm;
}

// ---------------------------------------------------------------------------
// K2: compact pruned row indices per batch (order irrelevant).
// ---------------------------------------------------------------------------
__global__ __launch_bounds__(256) void k_compact(const float* __restrict__ pruned,
                                                 int* __restrict__ cnt,
                                                 int* __restrict__ list) {
    int g = blockIdx.x * 256 + threadIdx.x;           // 0 .. B*N-1
    if (g >= BB * NN) return;
    if (pruned[g] != 0.0f) {
        int b = g >> 11;                              // g / N
        int n = g & (NN - 1);                         // g % N
        int pos = atomicAdd(&cnt[b], 1);
        list[b * NN + pos] = n;
    }
}

// ---------------------------------------------------------------------------
// K3: per pruned row, top-1 (with exact ties) over kept columns; emit merge
// edges: S[t] += w, A[t][:] += w * x[src][:], w = exp(max cosine sim).
// Block: 256 threads, ROWS pruned rows, full 2048-column sweep.
// Sims for the row tile are stored in LDS so the tie scan needs no recompute.
// ---------------------------------------------------------------------------
__global__ __launch_bounds__(256) void k_argmax_edges(
    const float* __restrict__ x,      // original x  [B,N,C]
    const float* __restrict__ xn,     // normalized  [B,N,C]
    const float* __restrict__ keep,   // [B,N]
    const int*   __restrict__ cnt,    // [B]
    const int*   __restrict__ list,   // [B,N]
    float* __restrict__ S,            // [B,N]   (zeroed)
    float* __restrict__ A) {          // [B,N,C] (zeroed; aliases d_out)

    __shared__ float sims[ROWS * NN];                  // 48 KB
    __shared__ __align__(16) float xrow[ROWS][CC];     // 1.5 KB
    __shared__ int   srow[ROWS];
    __shared__ float wmax[ROWS][4];
    __shared__ float bmax[ROWS];

    const int b    = blockIdx.y;
    const int tile = blockIdx.x;
    const int count = cnt[b];
    const int base  = tile * ROWS;
    if (base >= count) return;
    const int nrows = min(ROWS, count - base);
    const int tid   = threadIdx.x;

    // Stage source (pruned) row vectors of xn into LDS.
    for (int idx = tid; idx < ROWS * CC; idx += 256) {
        int r = idx >> 6, c = idx & 63;
        float val = 0.0f;
        if (r < nrows) {
            int n = list[b * NN + base + r];
            if (c == 0) srow[r] = n;
            val = xn[((size_t)b * NN + n) * CC + c];
        } else if (c == 0) {
            srow[r] = -1;
        }
        xrow[r][c] = val;
    }
    __syncthreads();

    int sr[ROWS];
#pragma unroll
    for (int r = 0; r < ROWS; ++r) sr[r] = srow[r];

    float tmax[ROWS];
#pragma unroll
    for (int r = 0; r < ROWS; ++r) tmax[r] = -3.0e38f;

    const float4* xn4 = (const float4*)(xn + (size_t)b * NN * CC);

    // 4 chunks of 512 columns; each thread owns 2 columns per chunk.
    for (int chunk = 0; chunk < 4; ++chunk) {
        int m0 = chunk * 512 + tid;
        int m1 = m0 + 256;
        float acc0[ROWS], acc1[ROWS];
#pragma unroll
        for (int r = 0; r < ROWS; ++r) { acc0[r] = 0.0f; acc1[r] = 0.0f; }
#pragma unroll
        for (int ccx = 0; ccx < 16; ++ccx) {
            float4 v0 = xn4[m0 * 16 + ccx];
            float4 v1 = xn4[m1 * 16 + ccx];
#pragma unroll
            for (int r = 0; r < ROWS; ++r) {
                float4 w = ((const float4*)xrow[r])[ccx];   // LDS broadcast
                acc0[r] = fmaf(w.x, v0.x, fmaf(w.y, v0.y,
                          fmaf(w.z, v0.z, fmaf(w.w, v0.w, acc0[r]))));
                acc1[r] = fmaf(w.x, v1.x, fmaf(w.y, v1.y,
                          fmaf(w.z, v1.z, fmaf(w.w, v1.w, acc1[r]))));
            }
        }
        float k0 = keep[b * NN + m0];
        float k1 = keep[b * NN + m1];
#pragma unroll
        for (int r = 0; r < ROWS; ++r) {
            float s0 = (k0 != 0.0f && m0 != sr[r]) ? acc0[r] : NEG100;
            float s1 = (k1 != 0.0f && m1 != sr[r]) ? acc1[r] : NEG100;
            sims[r * NN + m0] = s0;
            sims[r * NN + m1] = s1;
            tmax[r] = fmaxf(tmax[r], fmaxf(s0, s1));
        }
    }

    // Block max per row: wave shuffle-reduce, then cross-wave via LDS.
#pragma unroll
    for (int r = 0; r < ROWS; ++r) {
        float m = tmax[r];
#pragma unroll
        for (int off = 32; off > 0; off >>= 1)
            m = fmaxf(m, __shfl_xor(m, off, 64));
        if ((tid & 63) == 0) wmax[r][tid >> 6] = m;
    }
    __syncthreads();
    if (tid < ROWS)
        bmax[tid] = fmaxf(fmaxf(wmax[tid][0], wmax[tid][1]),
                          fmaxf(wmax[tid][2], wmax[tid][3]));
    __syncthreads();

    // Tie scan: every column whose sim equals the row max gets an edge.
    for (int r = 0; r < nrows; ++r) {
        float M = bmax[r];
        float w = expf(M);
        const float* xs = x + ((size_t)b * NN + sr[r]) * CC;
#pragma unroll
        for (int k = 0; k < 8; ++k) {
            int m = k * 256 + tid;
            if (sims[r * NN + m] == M) {
                atomicAdd(&S[b * NN + m], w);
                float* Ap = A + ((size_t)b * NN + m) * CC;
                for (int c = 0; c < CC; ++c)
                    atomicAdd(&Ap[c], w * xs[c]);
            }
        }
    }
}

// ---------------------------------------------------------------------------
// K4: out = (e*x + A) / (e + S).  A aliases d_out (in-place), float4.
// ---------------------------------------------------------------------------
__global__ __launch_bounds__(256) void k_finalize(const float* __restrict__ x,
                                                  const float* __restrict__ S,
                                                  float* __restrict__ out) {
    int i = blockIdx.x * 256 + threadIdx.x;     // float4 index
    int row = i >> 4;                           // 16 float4 per row (C=64)
    float inv = 1.0f / (E_CONST + S[row]);
    float4 xv = ((const float4*)x)[i];
    float4 av = ((float4*)out)[i];
    float4 o;
    o.x = (xv.x * E_CONST + av.x) * inv;
    o.y = (xv.y * E_CONST + av.y) * inv;
    o.z = (xv.z * E_CONST + av.z) * inv;
    o.w = (xv.w * E_CONST + av.w) * inv;
    ((float4*)out)[i] = o;
}

// ---------------------------------------------------------------------------
extern "C" void kernel_launch(void* const* d_in, const int* in_sizes, int n_in,
                              void* d_out, int out_size, void* d_ws, size_t ws_size,
                              hipStream_t stream) {
    const float* x      = (const float*)d_in[0];
    // d_in[1] (y) is unused by the reference computation.
    const float* keep   = (const float*)d_in[2];
    const float* pruned = (const float*)d_in[3];
    float* out = (float*)d_out;

    // Workspace layout: xn (8 MB) | S (128 KB) | cnt (256 B) | list (128 KB)
    char* ws = (char*)d_ws;
    float* xn  = (float*)ws;
    float* S   = (float*)(ws + (size_t)8 * 1024 * 1024);
    int*   cnt = (int*)  (ws + (size_t)8 * 1024 * 1024 + 131072);
    int*   list= (int*)  (ws + (size_t)8 * 1024 * 1024 + 131072 + 256);

    // Zero: A accumulator (aliased to d_out), S, cnt.  (S and cnt contiguous.)
    hipMemsetAsync(out, 0, (size_t)BB * NN * CC * sizeof(float), stream);
    hipMemsetAsync(S, 0, 131072 + 256, stream);

    k_normalize<<<BB * NN / 4, 256, 0, stream>>>(x, xn);
    k_compact<<<(BB * NN) / 256, 256, 0, stream>>>(pruned, cnt, list);

    dim3 g2((NN + ROWS - 1) / ROWS, BB);
    k_argmax_edges<<<g2, 256, 0, stream>>>(x, xn, keep, cnt, list, S, out);

    k_finalize<<<(BB * NN * CC / 4) / 256, 256, 0, stream>>>(x, S, out);
}

// Round 2
// 497.574 us; speedup vs baseline: 1.4274x; 1.4274x over previous
//
#include <hip/hip_runtime.h>
#include <math.h>

// Problem constants (B,N,C fixed by the reference setup).
#define BB 16
#define NN 2048
#define CC 64
#define TPB 256
#define RB 32          // pruned rows per block in K3
#define RW 8           // rows per wave (4 waves * 8 = 32)
#define TCOLS 128      // kept-column tile staged in LDS
#define PSTR 65        // LDS column stride (floats): 65%32=1 -> 2-way (free)
#define E_CONST 2.71828182845904523536f

// ---------------------------------------------------------------------------
// K1: classify tokens into kept / pruned compacted index lists.
// ---------------------------------------------------------------------------
__global__ __launch_bounds__(TPB) void k_compact(const float* __restrict__ keep,
                                                 int* __restrict__ cntP,
                                                 int* __restrict__ cntK,
                                                 int* __restrict__ listP,
                                                 int* __restrict__ listK) {
    int g = blockIdx.x * TPB + threadIdx.x;        // 0 .. B*N-1
    int b = g >> 11;
    int n = g & (NN - 1);
    if (keep[g] != 0.0f) {
        int p = atomicAdd(&cntK[b], 1);
        listK[b * NN + p] = n;
    } else {
        int p = atomicAdd(&cntP[b], 1);
        listP[b * NN + p] = n;
    }
}

// ---------------------------------------------------------------------------
// K2: gather + L2-normalize rows into packed buffers.
//   z==0: pruned rows  -> rowbuf (zero-padded to multiple of RB)
//   z==1: kept columns -> colbuf (zero-padded to multiple of TCOLS)
// One wave per packed slot.
// ---------------------------------------------------------------------------
__global__ __launch_bounds__(TPB) void k_gather(const float* __restrict__ x,
                                                const int* __restrict__ cntP,
                                                const int* __restrict__ cntK,
                                                const int* __restrict__ listP,
                                                const int* __restrict__ listK,
                                                float* __restrict__ rowbuf,
                                                float* __restrict__ colbuf) {
    int b    = blockIdx.y;
    int slot = blockIdx.x * 4 + (threadIdx.x >> 6);
    int lane = threadIdx.x & 63;
    int kb   = blockIdx.z;                          // 0=pruned, 1=kept
    int cnt  = kb ? cntK[b] : cntP[b];
    int rnd  = kb ? ((cnt + TCOLS - 1) & ~(TCOLS - 1))
                  : ((cnt + RB - 1) & ~(RB - 1));
    if (slot >= rnd) return;
    const int* list = (kb ? listK : listP) + b * NN;
    float* buf = (kb ? colbuf : rowbuf) + ((size_t)b * NN + slot) * CC;
    float o = 0.0f;
    if (slot < cnt) {
        int n   = list[slot];
        float v = x[((size_t)b * NN + n) * CC + lane];
        float sq = v * v;
#pragma unroll
        for (int off = 32; off > 0; off >>= 1)
            sq += __shfl_xor(sq, off, 64);
        o = v / (sqrtf(sq) + 1e-6f);
    }
    buf[lane] = o;
}

// ---------------------------------------------------------------------------
// K3: panel GEMM-argmax.  Block = 32 pruned rows x all kept cols.
// Thread tile: 8 rows x 2 cols, cols from a 128-col LDS tile, rows via
// wave-uniform loads (VMEM/scalar pipe, off the VALU critical path).
// Ties tracked with a per-(row,thread) running max + 32-bit tile bitmask.
// Edges emitted wave-cooperatively: one 64-lane atomic pass per edge.
// ---------------------------------------------------------------------------
__global__ __launch_bounds__(TPB) void k_argmax_edges(
    const float* __restrict__ x,       // [B,N,C] original
    const float* __restrict__ rowbuf,  // [B,N,C] packed normalized pruned rows
    const float* __restrict__ colbuf,  // [B,N,C] packed normalized kept cols
    const int*   __restrict__ cntP,
    const int*   __restrict__ cntK,
    const int*   __restrict__ listP,
    const int*   __restrict__ listK,
    float* __restrict__ S,             // [B,N] (zeroed)
    float* __restrict__ A) {           // [B,N,C] (zeroed; aliases d_out)

    const int b = blockIdx.y;
    const int P = cntP[b];
    const int K = cntK[b];
    const int base = blockIdx.x * RB;
    if (base >= P) return;

    const int tid = threadIdx.x;
    const int wid = tid >> 6;          // rowgroup == wave
    const int lig = tid & 63;

    __shared__ float tile[TCOLS * PSTR];   // 33,280 B

    const float4* rb4 = (const float4*)(rowbuf + ((size_t)b * NN + base) * CC);
    const float4* cb4 = (const float4*)(colbuf + (size_t)b * NN * CC);

    float    tmax[RW];
    unsigned msk[RW];
#pragma unroll
    for (int r = 0; r < RW; ++r) { tmax[r] = -INFINITY; msk[r] = 0u; }

    const int ntiles = (K + TCOLS - 1) / TCOLS;    // <= 16

    for (int t = 0; t < ntiles; ++t) {
        __syncthreads();
        // Stage 128 cols x 64 ch: coalesced float4 reads, padded LDS writes.
        for (int i = tid; i < TCOLS * 16; i += TPB) {
            int col = i >> 4, c4 = i & 15;
            float4 v = cb4[(size_t)(t * TCOLS + col) * 16 + c4];
            int a = col * PSTR + c4 * 4;
            tile[a] = v.x; tile[a + 1] = v.y; tile[a + 2] = v.z; tile[a + 3] = v.w;
        }
        __syncthreads();

        float acc[RW][2];
#pragma unroll
        for (int r = 0; r < RW; ++r) { acc[r][0] = 0.0f; acc[r][1] = 0.0f; }

#pragma unroll 4
        for (int c4 = 0; c4 < 16; ++c4) {
            float4 rv[RW];
#pragma unroll
            for (int r = 0; r < RW; ++r)
                rv[r] = rb4[(size_t)(wid * RW + r) * 16 + c4];   // wave-uniform
            float c0[4], c1[4];
#pragma unroll
            for (int j = 0; j < 4; ++j) {
                c0[j] = tile[lig * PSTR + c4 * 4 + j];
                c1[j] = tile[(lig + 64) * PSTR + c4 * 4 + j];
            }
#pragma unroll
            for (int r = 0; r < RW; ++r) {
                acc[r][0] = fmaf(rv[r].x, c0[0], fmaf(rv[r].y, c0[1],
                            fmaf(rv[r].z, c0[2], fmaf(rv[r].w, c0[3], acc[r][0]))));
                acc[r][1] = fmaf(rv[r].x, c1[0], fmaf(rv[r].y, c1[1],
                            fmaf(rv[r].z, c1[2], fmaf(rv[r].w, c1[3], acc[r][1]))));
            }
        }

        // Running max + tie bitmask update (2 bits per tile).
#pragma unroll
        for (int r = 0; r < RW; ++r) {
#pragma unroll
            for (int j = 0; j < 2; ++j) {
                int colp = t * TCOLS + j * 64 + lig;
                float s = (colp < K) ? acc[r][j] : -1.0e30f;
                unsigned bit = 1u << (t * 2 + j);
                if (s > tmax[r])      { tmax[r] = s; msk[r] = bit; }
                else if (s == tmax[r]) msk[r] |= bit;
            }
        }
    }

    // ---- Edge emission: per wave, per row. ----
    int vr = min(RB, P - base) - wid * RW;   // valid rows in this wave
    for (int r = 0; r < RW; ++r) {
        if (r >= vr) break;
        float m = tmax[r];
#pragma unroll
        for (int off = 32; off > 0; off >>= 1)
            m = fmaxf(m, __shfl_xor(m, off, 64));
        int   src = listP[b * NN + base + wid * RW + r];
        float xv  = x[((size_t)b * NN + src) * CC + lig];   // lane's channel
        float w   = expf(m);
        unsigned long long bal = __ballot(tmax[r] == m && msk[r] != 0u);
        while (bal) {
            int sl = __ffsll(bal) - 1;
            bal &= bal - 1;
            unsigned mm = __shfl(msk[r], sl);
            while (mm) {
                int bit = __ffs(mm) - 1;
                mm &= mm - 1;
                int colp = (bit >> 1) * TCOLS + (bit & 1) * 64 + sl;
                int realcol = listK[b * NN + colp];          // same addr, all lanes
                atomicAdd(&A[((size_t)b * NN + realcol) * CC + lig], w * xv);
                if (lig == 0) atomicAdd(&S[b * NN + realcol], w);
            }
        }
    }
}

// ---------------------------------------------------------------------------
// K4: out = (e*x + A) / (e + S).  A aliases d_out (in-place), float4.
// ---------------------------------------------------------------------------
__global__ __launch_bounds__(TPB) void k_finalize(const float* __restrict__ x,
                                                  const float* __restrict__ S,
                                                  float* __restrict__ out) {
    int i = blockIdx.x * TPB + threadIdx.x;     // float4 index
    int row = i >> 4;                           // 16 float4 per row (C=64)
    float inv = 1.0f / (E_CONST + S[row]);
    float4 xv = ((const float4*)x)[i];
    float4 av = ((float4*)out)[i];
    float4 o;
    o.x = (xv.x * E_CONST + av.x) * inv;
    o.y = (xv.y * E_CONST + av.y) * inv;
    o.z = (xv.z * E_CONST + av.z) * inv;
    o.w = (xv.w * E_CONST + av.w) * inv;
    ((float4*)out)[i] = o;
}

// ---------------------------------------------------------------------------
extern "C" void kernel_launch(void* const* d_in, const int* in_sizes, int n_in,
                              void* d_out, int out_size, void* d_ws, size_t ws_size,
                              hipStream_t stream) {
    const float* x    = (const float*)d_in[0];
    const float* keep = (const float*)d_in[2];
    float* out = (float*)d_out;

    // ws layout: rowbuf 8MB | colbuf 8MB | S 128KB | cntP/cntK 128B | listP 128KB | listK 128KB
    char* ws = (char*)d_ws;
    float* rowbuf = (float*)ws;
    float* colbuf = (float*)(ws + ((size_t)8 << 20));
    float* S      = (float*)(ws + ((size_t)16 << 20));
    int*   cntP   = (int*)(ws + ((size_t)16 << 20) + (128 << 10));
    int*   cntK   = cntP + 16;
    int*   listP  = (int*)((char*)(cntP + 32));
    int*   listK  = listP + BB * NN;

    // Zero: A accumulator (=d_out), S + counters (contiguous).
    hipMemsetAsync(out, 0, (size_t)BB * NN * CC * sizeof(float), stream);
    hipMemsetAsync(S, 0, (128 << 10) + 128, stream);

    k_compact<<<(BB * NN) / TPB, TPB, 0, stream>>>(keep, cntP, cntK, listP, listK);

    dim3 gg(NN / 4, BB, 2);
    k_gather<<<gg, TPB, 0, stream>>>(x, cntP, cntK, listP, listK, rowbuf, colbuf);

    dim3 ga(NN / RB, BB);
    k_argmax_edges<<<ga, TPB, 0, stream>>>(x, rowbuf, colbuf, cntP, cntK,
                                           listP, listK, S, out);

    k_finalize<<<(BB * NN * CC / 4) / TPB, TPB, 0, stream>>>(x, S, out);
}

// Round 3
// 199.096 us; speedup vs baseline: 3.5672x; 2.4992x over previous
//
#include <hip/hip_runtime.h>
#include <math.h>

// Problem constants (B,N,C fixed by the reference setup).
#define BB 16
#define NN 2048
#define CC 64
#define TPB 256
#define MROWS 32          // pruned rows per block (4 waves x 8 rows)
#define NCOLS 256         // kept-column tile (64 lanes x 4 consecutive cols)
#define E_CONST 2.71828182845904523536f

// ---------------------------------------------------------------------------
// K1: inv_norm[b,n] = 1 / (||x[b,n]|| + eps).  One wave per row.
// ---------------------------------------------------------------------------
__global__ __launch_bounds__(TPB) void k_norms(const float* __restrict__ x,
                                               float* __restrict__ invn) {
    int row  = blockIdx.x * 4 + (threadIdx.x >> 6);
    int lane = threadIdx.x & 63;
    float v  = x[row * CC + lane];
    float sq = v * v;
#pragma unroll
    for (int off = 32; off; off >>= 1) sq += __shfl_xor(sq, off, 64);
    if (lane == 0) invn[row] = 1.0f / (sqrtf(sq) + 1e-6f);
}

// ---------------------------------------------------------------------------
// K2: ballot-based compaction into kept / pruned lists.  One block per batch;
// no divergent global atomics (LDS counters + wave ballot positions).
// ---------------------------------------------------------------------------
__global__ __launch_bounds__(TPB) void k_compact(const float* __restrict__ keep,
                                                 int* __restrict__ cntP,
                                                 int* __restrict__ cntK,
                                                 int* __restrict__ listP,
                                                 int* __restrict__ listK) {
    const int b = blockIdx.x;
    const int tid = threadIdx.x, lane = tid & 63;
    __shared__ int cP, cK;
    if (tid == 0) { cP = 0; cK = 0; }
    __syncthreads();
    const unsigned long long lt = (lane == 63) ? 0x7fffffffffffffffull
                                               : ((1ull << lane) - 1ull);
#pragma unroll
    for (int it = 0; it < NN / TPB; ++it) {
        int n = it * TPB + tid;
        bool kp = keep[b * NN + n] != 0.0f;
        unsigned long long mk = __ballot(kp);
        int nk = __popcll(mk);
        int bk = 0, bp = 0;
        if (lane == 0) {
            bk = atomicAdd(&cK, nk);
            bp = atomicAdd(&cP, 64 - nk);
        }
        bk = __shfl(bk, 0); bp = __shfl(bp, 0);
        int pk = __popcll(mk & lt);
        if (kp) listK[b * NN + bk + pk] = n;
        else    listP[b * NN + bp + (lane - pk)] = n;
    }
    __syncthreads();
    if (tid == 0) { cntP[b] = cP; cntK[b] = cK; }
}

// ---------------------------------------------------------------------------
// K3: GEMM-argmax.  Block = 32 pruned rows; iterates kept cols in 256-tiles.
//  - rows: wave-uniform tokens -> readfirstlane -> s_load row fragments
//    (scalar pipe; FMA is v_fmac acc, sgpr, vgpr)
//  - cols: staged k-major in LDS (register transpose, ds_write_b128),
//    pre-scaled by inv_norm[col]; lane reads 4 consecutive cols per k.
//  - argmax value is dot * inv_c; inv_r applied only inside exp() (positive
//    common factor, does not change argmax / ties).
//  - ties: per-thread running max + 32-bit (tile,j) mask; emission per wave.
// ---------------------------------------------------------------------------
__global__ __launch_bounds__(TPB) void k_argmax(
    const float* __restrict__ x,      // [B,N,C]
    const float* __restrict__ invn,   // [B,N]
    const int*   __restrict__ cntP,
    const int*   __restrict__ cntK,
    const int*   __restrict__ listP,
    const int*   __restrict__ listK,
    float* __restrict__ S,            // [B,N]   zeroed
    float* __restrict__ A) {          // [B,N,C] zeroed; aliases d_out

    const int b = blockIdx.y;
    const int P = cntP[b], K = cntK[b];
    const int base = blockIdx.x * MROWS;
    if (base >= P) return;

    const int tid = threadIdx.x;
    const int wid = tid >> 6;
    const int lane = tid & 63;

    __shared__ __align__(16) float colT[CC * NCOLS];   // [k][col], 64 KB

    // Per-wave row tokens / pointers (wave-uniform -> scalar regs).
    int rtok[8];
    const float* rowp[8];
#pragma unroll
    for (int r = 0; r < 8; ++r) {
        int rid = base + wid * 8 + r;
        int tok = (rid < P) ? listP[b * NN + rid] : 0;
        tok = __builtin_amdgcn_readfirstlane(tok);
        rtok[r] = tok;
        rowp[r] = x + (size_t)(b * NN + tok) * CC;
    }

    float    tmax[8];
    unsigned msk[8];
#pragma unroll
    for (int r = 0; r < 8; ++r) { tmax[r] = -3.0e38f; msk[r] = 0u; }

    const float4* x4 = (const float4*)(x + (size_t)b * NN * CC);
    const int ntiles = (K + NCOLS - 1) / NCOLS;        // <= 8

    for (int t = 0; t < ntiles; ++t) {
        __syncthreads();   // previous tile's compute done before re-staging

        // ---- stage col tile, k-major, scaled by inv_c ----
        {
            int q = lane, p = wid;                      // q: col quad, p: k4 group
            int cb = t * NCOLS + q * 4;
            int   tk[4]; float iv[4];
#pragma unroll
            for (int c = 0; c < 4; ++c) {
                int colp = cb + c;
                bool ok = colp < K;
                tk[c] = ok ? listK[b * NN + colp] : 0;
                iv[c] = ok ? invn[b * NN + tk[c]] : 0.0f;
            }
#pragma unroll
            for (int kk = 0; kk < 4; ++kk) {
                int k4 = p * 4 + kk;
                float4 w0 = x4[(size_t)tk[0] * 16 + k4];
                float4 w1 = x4[(size_t)tk[1] * 16 + k4];
                float4 w2 = x4[(size_t)tk[2] * 16 + k4];
                float4 w3 = x4[(size_t)tk[3] * 16 + k4];
                w0.x *= iv[0]; w0.y *= iv[0]; w0.z *= iv[0]; w0.w *= iv[0];
                w1.x *= iv[1]; w1.y *= iv[1]; w1.z *= iv[1]; w1.w *= iv[1];
                w2.x *= iv[2]; w2.y *= iv[2]; w2.z *= iv[2]; w2.w *= iv[2];
                w3.x *= iv[3]; w3.y *= iv[3]; w3.z *= iv[3]; w3.w *= iv[3];
                float4 o;
                o.x = w0.x; o.y = w1.x; o.z = w2.x; o.w = w3.x;
                *(float4*)&colT[(k4 * 4 + 0) * NCOLS + q * 4] = o;
                o.x = w0.y; o.y = w1.y; o.z = w2.y; o.w = w3.y;
                *(float4*)&colT[(k4 * 4 + 1) * NCOLS + q * 4] = o;
                o.x = w0.z; o.y = w1.z; o.z = w2.z; o.w = w3.z;
                *(float4*)&colT[(k4 * 4 + 2) * NCOLS + q * 4] = o;
                o.x = w0.w; o.y = w1.w; o.z = w2.w; o.w = w3.w;
                *(float4*)&colT[(k4 * 4 + 3) * NCOLS + q * 4] = o;
            }
        }
        __syncthreads();

        // ---- compute: 8 rows x 4 cols per thread over k=0..63 ----
        float acc[8][4];
#pragma unroll
        for (int r = 0; r < 8; ++r)
#pragma unroll
            for (int j = 0; j < 4; ++j) acc[r][j] = 0.0f;

#pragma unroll 2
        for (int k4 = 0; k4 < 16; ++k4) {
            float4 rv[8];
#pragma unroll
            for (int r = 0; r < 8; ++r)
                rv[r] = *(const float4*)(rowp[r] + k4 * 4);   // s_load_dwordx4
#pragma unroll
            for (int kk = 0; kk < 4; ++kk) {
                float4 cv = *(const float4*)&colT[(k4 * 4 + kk) * NCOLS + lane * 4];
#pragma unroll
                for (int r = 0; r < 8; ++r) {
                    float rk = (kk == 0) ? rv[r].x : (kk == 1) ? rv[r].y
                             : (kk == 2) ? rv[r].z : rv[r].w;
                    acc[r][0] = fmaf(rk, cv.x, acc[r][0]);
                    acc[r][1] = fmaf(rk, cv.y, acc[r][1]);
                    acc[r][2] = fmaf(rk, cv.z, acc[r][2]);
                    acc[r][3] = fmaf(rk, cv.w, acc[r][3]);
                }
            }
        }

        // ---- running max + tie mask ----
#pragma unroll
        for (int r = 0; r < 8; ++r)
#pragma unroll
            for (int j = 0; j < 4; ++j) {
                int colp = t * NCOLS + lane * 4 + j;
                float s = (colp < K) ? acc[r][j] : -1.0e30f;
                unsigned bit = 1u << ((t << 2) | j);
                if (s > tmax[r])       { tmax[r] = s; msk[r] = bit; }
                else if (s == tmax[r])  msk[r] |= bit;
            }
    }

    // ---- edge emission: per wave, per valid row ----
    int nvr = P - base - wid * 8;          // may exceed 8; loop caps at 8
    for (int r = 0; r < 8; ++r) {
        if (r >= nvr) break;
        float m = tmax[r];
#pragma unroll
        for (int off = 32; off; off >>= 1) m = fmaxf(m, __shfl_xor(m, off, 64));
        int src = rtok[r];
        float w  = expf(m * invn[b * NN + src]);
        float xv = x[(size_t)(b * NN + src) * CC + lane];
        unsigned long long bal = __ballot(tmax[r] == m);
        while (bal) {
            int sl = __ffsll((unsigned long long)bal) - 1;
            bal &= bal - 1;
            unsigned mm = __shfl(msk[r], sl);
            while (mm) {
                int bit = __ffs(mm) - 1;
                mm &= mm - 1;
                int colp = ((bit >> 2) << 8) + sl * 4 + (bit & 3);
                int dst = listK[b * NN + colp];
                atomicAdd(&A[(size_t)(b * NN + dst) * CC + lane], w * xv);
                if (lane == 0) atomicAdd(&S[b * NN + dst], w);
            }
        }
    }
}

// ---------------------------------------------------------------------------
// K4: out = (e*x + A) / (e + S).  A aliases d_out (in-place), float4.
// ---------------------------------------------------------------------------
__global__ __launch_bounds__(TPB) void k_finalize(const float* __restrict__ x,
                                                  const float* __restrict__ S,
                                                  float* __restrict__ out) {
    int i = blockIdx.x * TPB + threadIdx.x;
    int row = i >> 4;
    float inv = 1.0f / (E_CONST + S[row]);
    float4 xv = ((const float4*)x)[i];
    float4 av = ((float4*)out)[i];
    float4 o;
    o.x = (xv.x * E_CONST + av.x) * inv;
    o.y = (xv.y * E_CONST + av.y) * inv;
    o.z = (xv.z * E_CONST + av.z) * inv;
    o.w = (xv.w * E_CONST + av.w) * inv;
    ((float4*)out)[i] = o;
}

// ---------------------------------------------------------------------------
extern "C" void kernel_launch(void* const* d_in, const int* in_sizes, int n_in,
                              void* d_out, int out_size, void* d_ws, size_t ws_size,
                              hipStream_t stream) {
    const float* x    = (const float*)d_in[0];
    const float* keep = (const float*)d_in[2];
    float* out = (float*)d_out;

    // ws: invn 128KB | S 128KB | cnts 128B | listP 128KB | listK 128KB
    char* ws = (char*)d_ws;
    float* invn = (float*)ws;
    float* S    = (float*)(ws + (128 << 10));
    int*   cntP = (int*)(ws + (256 << 10));
    int*   cntK = cntP + 16;
    int*   listP = (int*)(ws + (256 << 10) + 128);
    int*   listK = listP + BB * NN;

    hipMemsetAsync(out, 0, (size_t)BB * NN * CC * sizeof(float), stream);
    hipMemsetAsync(S, 0, 128 << 10, stream);

    k_norms<<<BB * NN / 4, TPB, 0, stream>>>(x, invn);
    k_compact<<<BB, TPB, 0, stream>>>(keep, cntP, cntK, listP, listK);

    dim3 ga(NN / MROWS, BB);
    k_argmax<<<ga, TPB, 0, stream>>>(x, invn, cntP, cntK, listP, listK, S, out);

    k_finalize<<<(BB * NN * CC / 4) / TPB, TPB, 0, stream>>>(x, S, out);
}

// Round 4
// 197.502 us; speedup vs baseline: 3.5960x; 1.0081x over previous
//
#include <hip/hip_runtime.h>
#include <math.h>

// Problem constants (B,N,C fixed by the reference setup).
#define BB 16
#define NN 2048
#define CC 64
#define TPB 256
#define MROWS 32          // pruned rows per block (4 waves x 8 rows)
#define NCOLS 256         // kept-column tile (64 lanes x 4 consecutive cols)
#define E_CONST 2.71828182845904523536f

// ---------------------------------------------------------------------------
// K_pre (fused): every block computes inv-norms for 4 rows and zeroes the
// matching slice of out (the A accumulator).  Blocks 0..BB-1 additionally
// run ballot-based compaction for batch b = blockIdx.x and zero S[b,:].
// ---------------------------------------------------------------------------
__global__ __launch_bounds__(TPB) void k_pre(const float* __restrict__ x,
                                             const float* __restrict__ keep,
                                             float* __restrict__ invn,
                                             float* __restrict__ outz,
                                             float* __restrict__ S,
                                             int* __restrict__ cntP,
                                             int* __restrict__ cntK,
                                             int* __restrict__ listP,
                                             int* __restrict__ listK) {
    __shared__ int cP, cK;
    const int tid = threadIdx.x, lane = tid & 63;

    // ---- norms + out-zero (all blocks) ----
    int row = blockIdx.x * 4 + (tid >> 6);
    float v = x[row * CC + lane];
    float sq = v * v;
#pragma unroll
    for (int off = 32; off; off >>= 1) sq += __shfl_xor(sq, off, 64);
    if (lane == 0) invn[row] = 1.0f / (sqrtf(sq) + 1e-6f);
    outz[row * CC + lane] = 0.0f;

    // ---- compaction + S-zero (blocks 0..BB-1) ----
    const int b = blockIdx.x;
    if (b >= BB) return;
    if (tid == 0) { cP = 0; cK = 0; }
    __syncthreads();
    for (int i = tid; i < NN; i += TPB) S[b * NN + i] = 0.0f;
    const unsigned long long lt = (lane == 63) ? 0x7fffffffffffffffull
                                               : ((1ull << lane) - 1ull);
#pragma unroll
    for (int it = 0; it < NN / TPB; ++it) {
        int n = it * TPB + tid;
        bool kp = keep[b * NN + n] != 0.0f;
        unsigned long long mk = __ballot(kp);
        int nk = __popcll(mk);
        int bk = 0, bp = 0;
        if (lane == 0) {
            bk = atomicAdd(&cK, nk);
            bp = atomicAdd(&cP, 64 - nk);
        }
        bk = __shfl(bk, 0); bp = __shfl(bp, 0);
        int pk = __popcll(mk & lt);
        if (kp) listK[b * NN + bk + pk] = n;
        else    listP[b * NN + bp + (lane - pk)] = n;
    }
    __syncthreads();
    if (tid == 0) { cntP[b] = cP; cntK[b] = cK; }
}

// ---------------------------------------------------------------------------
// K3: GEMM-argmax.  Block = 32 pruned rows; kept cols iterated in 256-tiles.
// Inner loop touches ONLY LDS (in-order lgkmcnt -> fine-grained waits):
//  - rows staged once into rowT[32][64] (raw x); read as wave-uniform
//    broadcast ds_read_b128 (conflict-free).
//  - cols staged per tile, k-major, pre-scaled by inv_norm[col].
//  - argmax over dot*inv_c; inv_r folded into exp() only (positive common
//    factor per row -> same argmax / tie set).
//  - ties: per-thread running max + 32-bit (tile,j) bitmask (8 tiles x 4).
// ---------------------------------------------------------------------------
__global__ __launch_bounds__(TPB, 2) void k_argmax(
    const float* __restrict__ x,      // [B,N,C]
    const float* __restrict__ invn,   // [B,N]
    const int*   __restrict__ cntP,
    const int*   __restrict__ cntK,
    const int*   __restrict__ listP,
    const int*   __restrict__ listK,
    float* __restrict__ S,            // [B,N]   zeroed by k_pre
    float* __restrict__ A) {          // [B,N,C] zeroed by k_pre; aliases d_out

    const int b = blockIdx.y;
    const int P = cntP[b], K = cntK[b];
    const int base = blockIdx.x * MROWS;
    if (base >= P) return;

    const int tid = threadIdx.x;
    const int wid = tid >> 6;
    const int lane = tid & 63;

    __shared__ __align__(16) float colT[CC * NCOLS];    // 64 KB, [k][col]
    __shared__ __align__(16) float rowT[MROWS * CC];    //  8 KB, [row][k]

    const float4* x4 = (const float4*)(x + (size_t)b * NN * CC);

    // ---- stage rows once (raw x; padding rows use token 0, never emitted) --
    for (int i = tid; i < MROWS * 16; i += TPB) {
        int rid = base + (i >> 4);
        int tok = (rid < P) ? listP[b * NN + rid] : 0;
        ((float4*)rowT)[i] = x4[(size_t)tok * 16 + (i & 15)];
    }
    int rtok[8];
#pragma unroll
    for (int r = 0; r < 8; ++r) {
        int rid = base + wid * 8 + r;
        int tok = (rid < P) ? listP[b * NN + rid] : 0;
        rtok[r] = __builtin_amdgcn_readfirstlane(tok);
    }

    float    tmax[8];
    unsigned msk[8];
#pragma unroll
    for (int r = 0; r < 8; ++r) { tmax[r] = -3.0e38f; msk[r] = 0u; }

    const int ntiles = (K + NCOLS - 1) / NCOLS;         // <= 8

    for (int t = 0; t < ntiles; ++t) {
        __syncthreads();   // rowT ready (t=0) / prev compute done (t>0)

        // ---- stage col tile, k-major, scaled by inv_c ----
        {
            int q = lane, p = wid;                      // col quad / k4 group
            int cb = t * NCOLS + q * 4;
            int tk[4]; float iv[4];
#pragma unroll
            for (int c = 0; c < 4; ++c) {
                int colp = cb + c;
                bool ok = colp < K;
                tk[c] = ok ? listK[b * NN + colp] : 0;
                iv[c] = ok ? invn[b * NN + tk[c]] : 0.0f;
            }
#pragma unroll
            for (int kk = 0; kk < 4; ++kk) {
                int k4 = p * 4 + kk;
                float4 w0 = x4[(size_t)tk[0] * 16 + k4];
                float4 w1 = x4[(size_t)tk[1] * 16 + k4];
                float4 w2 = x4[(size_t)tk[2] * 16 + k4];
                float4 w3 = x4[(size_t)tk[3] * 16 + k4];
                w0.x *= iv[0]; w0.y *= iv[0]; w0.z *= iv[0]; w0.w *= iv[0];
                w1.x *= iv[1]; w1.y *= iv[1]; w1.z *= iv[1]; w1.w *= iv[1];
                w2.x *= iv[2]; w2.y *= iv[2]; w2.z *= iv[2]; w2.w *= iv[2];
                w3.x *= iv[3]; w3.y *= iv[3]; w3.z *= iv[3]; w3.w *= iv[3];
                float4 o;
                o.x = w0.x; o.y = w1.x; o.z = w2.x; o.w = w3.x;
                *(float4*)&colT[(k4 * 4 + 0) * NCOLS + q * 4] = o;
                o.x = w0.y; o.y = w1.y; o.z = w2.y; o.w = w3.y;
                *(float4*)&colT[(k4 * 4 + 1) * NCOLS + q * 4] = o;
                o.x = w0.z; o.y = w1.z; o.z = w2.z; o.w = w3.z;
                *(float4*)&colT[(k4 * 4 + 2) * NCOLS + q * 4] = o;
                o.x = w0.w; o.y = w1.w; o.z = w2.w; o.w = w3.w;
                *(float4*)&colT[(k4 * 4 + 3) * NCOLS + q * 4] = o;
            }
        }
        __syncthreads();

        // ---- compute: 8 rows x 4 cols per thread; pure LDS inner loop ----
        float acc[8][4];
#pragma unroll
        for (int r = 0; r < 8; ++r)
#pragma unroll
            for (int j = 0; j < 4; ++j) acc[r][j] = 0.0f;

#pragma unroll 4
        for (int k4 = 0; k4 < 16; ++k4) {
            float4 rv[8];
#pragma unroll
            for (int r = 0; r < 8; ++r)   // wave-uniform broadcast ds_read_b128
                rv[r] = *(const float4*)&rowT[(wid * 8 + r) * CC + k4 * 4];
#pragma unroll
            for (int kk = 0; kk < 4; ++kk) {
                float4 cv = *(const float4*)&colT[(k4 * 4 + kk) * NCOLS + lane * 4];
#pragma unroll
                for (int r = 0; r < 8; ++r) {
                    float rk = (kk == 0) ? rv[r].x : (kk == 1) ? rv[r].y
                             : (kk == 2) ? rv[r].z : rv[r].w;
                    acc[r][0] = fmaf(rk, cv.x, acc[r][0]);
                    acc[r][1] = fmaf(rk, cv.y, acc[r][1]);
                    acc[r][2] = fmaf(rk, cv.z, acc[r][2]);
                    acc[r][3] = fmaf(rk, cv.w, acc[r][3]);
                }
            }
        }

        // ---- running max + tie mask ----
#pragma unroll
        for (int r = 0; r < 8; ++r)
#pragma unroll
            for (int j = 0; j < 4; ++j) {
                int colp = t * NCOLS + lane * 4 + j;
                float s = (colp < K) ? acc[r][j] : -1.0e30f;
                unsigned bit = 1u << ((t << 2) | j);
                if (s > tmax[r])       { tmax[r] = s; msk[r] = bit; }
                else if (s == tmax[r])  msk[r] |= bit;
            }
    }

    // ---- edge emission: per wave, per valid row ----
    int nvr = P - base - wid * 8;
    for (int r = 0; r < 8; ++r) {
        if (r >= nvr) break;
        float m = tmax[r];
#pragma unroll
        for (int off = 32; off; off >>= 1) m = fmaxf(m, __shfl_xor(m, off, 64));
        int src = rtok[r];
        float w  = expf(m * invn[b * NN + src]);
        float xv = x[(size_t)(b * NN + src) * CC + lane];
        unsigned long long bal = __ballot(tmax[r] == m && msk[r] != 0u);
        while (bal) {
            int sl = __ffsll(bal) - 1;
            bal &= bal - 1;
            unsigned mm = __shfl(msk[r], sl);
            while (mm) {
                int bit = __ffs(mm) - 1;
                mm &= mm - 1;
                int colp = ((bit >> 2) << 8) + sl * 4 + (bit & 3);
                int dst = listK[b * NN + colp];
                atomicAdd(&A[(size_t)(b * NN + dst) * CC + lane], w * xv);
                if (lane == 0) atomicAdd(&S[b * NN + dst], w);
            }
        }
    }
}

// ---------------------------------------------------------------------------
// K4: out = (e*x + A) / (e + S).  A aliases d_out (in-place), float4.
// ---------------------------------------------------------------------------
__global__ __launch_bounds__(TPB) void k_finalize(const float* __restrict__ x,
                                                  const float* __restrict__ S,
                                                  float* __restrict__ out) {
    int i = blockIdx.x * TPB + threadIdx.x;
    int row = i >> 4;
    float inv = 1.0f / (E_CONST + S[row]);
    float4 xv = ((const float4*)x)[i];
    float4 av = ((float4*)out)[i];
    float4 o;
    o.x = (xv.x * E_CONST + av.x) * inv;
    o.y = (xv.y * E_CONST + av.y) * inv;
    o.z = (xv.z * E_CONST + av.z) * inv;
    o.w = (xv.w * E_CONST + av.w) * inv;
    ((float4*)out)[i] = o;
}

// ---------------------------------------------------------------------------
extern "C" void kernel_launch(void* const* d_in, const int* in_sizes, int n_in,
                              void* d_out, int out_size, void* d_ws, size_t ws_size,
                              hipStream_t stream) {
    const float* x    = (const float*)d_in[0];
    const float* keep = (const float*)d_in[2];
    float* out = (float*)d_out;

    // ws: invn 128KB | S 128KB | cnts 128B | listP 128KB | listK 128KB
    char* ws = (char*)d_ws;
    float* invn = (float*)ws;
    float* S    = (float*)(ws + (128 << 10));
    int*   cntP = (int*)(ws + (256 << 10));
    int*   cntK = cntP + 16;
    int*   listP = (int*)(ws + (256 << 10) + 128);
    int*   listK = listP + BB * NN;

    k_pre<<<BB * NN / 4, TPB, 0, stream>>>(x, keep, invn, out, S,
                                           cntP, cntK, listP, listK);

    dim3 ga(NN / MROWS, BB);
    k_argmax<<<ga, TPB, 0, stream>>>(x, invn, cntP, cntK, listP, listK, S, out);

    k_finalize<<<(BB * NN * CC / 4) / TPB, TPB, 0, stream>>>(x, S, out);
}

// Round 5
// 182.942 us; speedup vs baseline: 3.8822x; 1.0796x over previous
//
#include <hip/hip_runtime.h>
#include <math.h>

// Problem constants (B,N,C fixed by the reference setup).
#define BB 16
#define NN 2048
#define CC 64
#define TPB 256
#define MROWS 32          // pruned rows per block (4 waves x 8 rows)
#define TILE 512          // kept-col tile per wave iteration (64 lanes x 8)
#define E_CONST 2.71828182845904523536f

// ---------------------------------------------------------------------------
// K_pre (fused): every block computes inv-norms for 4 rows and zeroes the
// matching slice of out (the A accumulator).  Blocks 0..BB-1 additionally
// run ballot-based compaction for batch b = blockIdx.x and zero S[b,:].
// ---------------------------------------------------------------------------
__global__ __launch_bounds__(TPB) void k_pre(const float* __restrict__ x,
                                             const float* __restrict__ keep,
                                             float* __restrict__ invn,
                                             float* __restrict__ outz,
                                             float* __restrict__ S,
                                             int* __restrict__ cntP,
                                             int* __restrict__ cntK,
                                             int* __restrict__ listP,
                                             int* __restrict__ listK) {
    __shared__ int cP, cK;
    const int tid = threadIdx.x, lane = tid & 63;

    // ---- norms + out-zero (all blocks) ----
    int row = blockIdx.x * 4 + (tid >> 6);
    float v = x[row * CC + lane];
    float sq = v * v;
#pragma unroll
    for (int off = 32; off; off >>= 1) sq += __shfl_xor(sq, off, 64);
    if (lane == 0) invn[row] = 1.0f / (sqrtf(sq) + 1e-6f);
    outz[row * CC + lane] = 0.0f;

    // ---- compaction + S-zero (blocks 0..BB-1) ----
    const int b = blockIdx.x;
    if (b >= BB) return;
    if (tid == 0) { cP = 0; cK = 0; }
    __syncthreads();
    for (int i = tid; i < NN; i += TPB) S[b * NN + i] = 0.0f;
    const unsigned long long lt = (lane == 63) ? 0x7fffffffffffffffull
                                               : ((1ull << lane) - 1ull);
#pragma unroll
    for (int it = 0; it < NN / TPB; ++it) {
        int n = it * TPB + tid;
        bool kp = keep[b * NN + n] != 0.0f;
        unsigned long long mk = __ballot(kp);
        int nk = __popcll(mk);
        int bk = 0, bp = 0;
        if (lane == 0) {
            bk = atomicAdd(&cK, nk);
            bp = atomicAdd(&cP, 64 - nk);
        }
        bk = __shfl(bk, 0); bp = __shfl(bp, 0);
        int pk = __popcll(mk & lt);
        if (kp) listK[b * NN + bk + pk] = n;
        else    listP[b * NN + bp + (lane - pk)] = n;
    }
    __syncthreads();
    if (tid == 0) { cntP[b] = cP; cntK[b] = cK; }
}

// ---------------------------------------------------------------------------
// K_pre2: build colM[b][k4][colp] as float4 (the 4 k-values k4*4..k4*4+3 of
// kept column colp, scaled by its inv-norm; zero beyond K).  Layout is
// k4-minor float4, so both this kernel's writes and k_argmax's reads are
// perfectly coalesced -- no transpose anywhere.
// ---------------------------------------------------------------------------
__global__ __launch_bounds__(TPB) void k_pre2(const float* __restrict__ x,
                                              const float* __restrict__ invn,
                                              const int* __restrict__ cntK,
                                              const int* __restrict__ listK,
                                              float4* __restrict__ colM) {
    const int b = blockIdx.y;
    const int colp = blockIdx.x * TPB + threadIdx.x;
    const int K = cntK[b];
    bool ok = colp < K;
    int tok = ok ? listK[b * NN + colp] : 0;
    float iv = ok ? invn[b * NN + tok] : 0.0f;
    const float4* x4 = (const float4*)(x + (size_t)b * NN * CC);
#pragma unroll
    for (int k4 = 0; k4 < 16; ++k4) {
        float4 w = x4[(size_t)tok * 16 + k4];
        w.x *= iv; w.y *= iv; w.z *= iv; w.w *= iv;
        colM[((size_t)(b * 16 + k4)) * NN + colp] = w;
    }
}

// ---------------------------------------------------------------------------
// K3: GEMM-argmax, zero LDS / zero barriers.  Wave = 8 pruned rows; iterates
// kept cols in 512-col tiles (8 float4 col streams per lane).
//  - rows: 8 wave-uniform 16-B loads per k4 (coalesced to one L2 request).
//  - cols: 8 coalesced global_load_dwordx4 per k4 from precomputed colM.
//  - acc[r][j] += dot4(rv[r], cv[j]); single vmcnt domain, compiler pipelines.
//  - ties: per-thread running max + 32-bit (tile,j) bitmask (4 tiles x 8).
// ---------------------------------------------------------------------------
__global__ __launch_bounds__(TPB, 2) void k_argmax(
    const float* __restrict__ x,      // [B,N,C]
    const float4* __restrict__ colM,  // [B,16,N] float4
    const float* __restrict__ invn,   // [B,N]
    const int*   __restrict__ cntP,
    const int*   __restrict__ cntK,
    const int*   __restrict__ listP,
    const int*   __restrict__ listK,
    float* __restrict__ S,            // [B,N]   zeroed by k_pre
    float* __restrict__ A) {          // [B,N,C] zeroed by k_pre; aliases d_out

    const int b = blockIdx.y;
    const int P = cntP[b], K = cntK[b];
    const int base = blockIdx.x * MROWS;
    if (base >= P) return;

    const int tid = threadIdx.x;
    const int wid = tid >> 6;
    const int lane = tid & 63;

    // Wave-uniform row tokens.
    int rtok[8];
#pragma unroll
    for (int r = 0; r < 8; ++r) {
        int rid = base + wid * 8 + r;
        int tok = (rid < P) ? listP[b * NN + rid] : 0;
        rtok[r] = __builtin_amdgcn_readfirstlane(tok);
    }
    const float4* x4 = (const float4*)(x + (size_t)b * NN * CC);
    const float4* cm = colM + (size_t)b * 16 * NN;

    float    tmax[8];
    unsigned msk[8];
#pragma unroll
    for (int r = 0; r < 8; ++r) { tmax[r] = -3.0e38f; msk[r] = 0u; }

    const int ntiles = (K + TILE - 1) / TILE;          // <= 4

    for (int t = 0; t < ntiles; ++t) {
        float acc[8][8];
#pragma unroll
        for (int r = 0; r < 8; ++r)
#pragma unroll
            for (int j = 0; j < 8; ++j) acc[r][j] = 0.0f;

        const int cbase = t * TILE + lane * 4;         // this lane's first col

#pragma unroll 2
        for (int k4 = 0; k4 < 16; ++k4) {
            float4 rv[8];
#pragma unroll
            for (int r = 0; r < 8; ++r)                // wave-uniform 16B loads
                rv[r] = x4[(size_t)rtok[r] * 16 + k4];
            const float4* cmk = cm + (size_t)k4 * NN + t * (TILE / 4) + lane;
            float4 cv[8];
#pragma unroll
            for (int j = 0; j < 8; ++j)                // coalesced b128 loads
                cv[j] = cmk[j * 64];
#pragma unroll
            for (int r = 0; r < 8; ++r)
#pragma unroll
                for (int j = 0; j < 8; ++j)
                    acc[r][j] = fmaf(rv[r].x, cv[j].x,
                                fmaf(rv[r].y, cv[j].y,
                                fmaf(rv[r].z, cv[j].z,
                                fmaf(rv[r].w, cv[j].w, acc[r][j]))));
        }

        // ---- running max + tie mask ----
        // lane's col for (t,j): (t*128 + j*16 + lane... ) see decode below:
        // col quad index = t*128 + j*64/4?  Actual: col = (t*128 + j*16?) --
        // we use: col = t*TILE + (j*64 + lane... no: cv[j] covers col quad
        // (t*128 + j*64 + lane)?? -- decode: cv[j] = cm[k4][t*128 + lane + j*64]
        // -> col quad q = t*128 + j*64 + lane is WRONG since j*64 spans 512.
        // Correct: quad q = t*128 + j*64 + lane only valid j<2.  We instead
        // defined cmk offset j*64 quads => q = t*128 + j*64 + lane, cols 4q..4q+3.
        // TILE=512 -> quads per tile = 128; j*64 for j=0..7 exceeds... so the
        // true mapping is q = t*128 + (j & 1) * 64 + lane + (j >> 1) * ??? --
        // To keep it simple we make TILE cover 8*64 quads = 2048 cols? No.
#pragma unroll
        for (int r = 0; r < 8; ++r)
#pragma unroll
            for (int j = 0; j < 8; ++j) {
                int q = t * (TILE / 4) + j * 64 + lane;   // col quad -- see note
                (void)q;
            }
        // NOTE: the mapping above is resolved by redefining TILE iteration:
        // we actually iterate quads q = t*128 + lane + j*64 with j<2 only.
        // To keep 8 col streams we instead interpret the loop as covering
        // 8*64 = 512 quads = 2048 cols when ntiles==1.  For K<=2048 we set
        // ntiles=1 and j spans the whole batch:
        break;
    }

    // The implementation above is replaced below (single-pass, j = col block).
    // ---- Recompute cleanly: single tile pass, 8 col-blocks of 256 cols ----
    {
#pragma unroll
        for (int r = 0; r < 8; ++r) { tmax[r] = -3.0e38f; msk[r] = 0u; }
        float acc[8][8];
#pragma unroll
        for (int r = 0; r < 8; ++r)
#pragma unroll
            for (int j = 0; j < 8; ++j) acc[r][j] = 0.0f;

        const int nj = (K + 255) >> 8;                 // active 256-col blocks

#pragma unroll 2
        for (int k4 = 0; k4 < 16; ++k4) {
            float4 rv[8];
#pragma unroll
            for (int r = 0; r < 8; ++r)
                rv[r] = x4[(size_t)rtok[r] * 16 + k4];
            const float4* cmk = cm + (size_t)k4 * (NN / 4) * 4 + lane;
            float4 cv[8];
#pragma unroll
            for (int j = 0; j < 8; ++j)
                cv[j] = cmk[j * 64];                   // quad = j*64 + lane
#pragma unroll
            for (int r = 0; r < 8; ++r)
#pragma unroll
                for (int j = 0; j < 8; ++j)
                    acc[r][j] = fmaf(rv[r].x, cv[j].x,
                                fmaf(rv[r].y, cv[j].y,
                                fmaf(rv[r].z, cv[j].z,
                                fmaf(rv[r].w, cv[j].w, acc[r][j]))));
        }
        (void)nj;

#pragma unroll
        for (int r = 0; r < 8; ++r)
#pragma unroll
            for (int j = 0; j < 8; ++j) {
                int colq = j * 64 + lane;              // col quad 0..511
                // cols 4*colq .. 4*colq+3; padded cols have colM==0 and are
                // excluded because sim 0 < any real max?  NOT guaranteed ->
                // exclude explicitly: quad fully below K? handle per-element.
                float s = acc[r][j];
                if (4 * colq >= K) s = -1.0e30f;       // whole quad padded
                unsigned bit = 1u << j;                 // j identifies block
                // per-quad tie granularity is wrong if K cuts inside a quad;
                // colM zero-pads those lanes so dot==partial?? No: colM is 0
                // for colp>=K *per column*, and acc[r][j] is the dot for ONE
                // column (4*colq+0..3?) -- NO: cv[j] is the k-quad of column
                // quad colq... each float4 = 4 k's of ONE column colp=colq??
                // colM[b][k4][colp] -> cm index (k4*NN... ) uses colp up to
                // 2047; quad index colq*?? CORRECT: colp == j*64+lane? That's
                // only 512 of 2048 columns!
                tmax[r] = fmaxf(tmax[r], s);
                (void)bit;
            }
    }
    // (decode resolved in final version below -- see k_argmax_v2)
}

// ===========================================================================
// FINAL clean implementation (the kernel above is unused; kept minimal).
// colp (0..2047) is covered by j in 0..7 blocks of 256 lanes?? lanes=64 ->
// colp = j*256 + seg*64 + lane with seg from an outer loop of 4.
// We iterate seg 0..3; per seg: 8 col streams j -> colp = seg*512?? Final
// mapping (used below): colp = c_outer*512 + j*64 + lane, c_outer 0..3.
// ===========================================================================
__global__ __launch_bounds__(TPB, 2) void k_argmax_v2(
    const float* __restrict__ x,
    const float4* __restrict__ colM,   // [B][16][2048] float4 (k-quad minor)
    const float* __restrict__ invn,
    const int*   __restrict__ cntP,
    const int*   __restrict__ cntK,
    const int*   __restrict__ listP,
    const int*   __restrict__ listK,
    float* __restrict__ S,
    float* __restrict__ A) {

    const int b = blockIdx.y;
    const int P = cntP[b], K = cntK[b];
    const int base = blockIdx.x * MROWS;
    if (base >= P) return;

    const int tid = threadIdx.x;
    const int wid = tid >> 6;
    const int lane = tid & 63;

    int rtok[8];
#pragma unroll
    for (int r = 0; r < 8; ++r) {
        int rid = base + wid * 8 + r;
        int tok = (rid < P) ? listP[b * NN + rid] : 0;
        rtok[r] = __builtin_amdgcn_readfirstlane(tok);
    }
    const float4* x4 = (const float4*)(x + (size_t)b * NN * CC);
    const float4* cm = colM + (size_t)b * 16 * NN;

    float    tmax[8];
    unsigned msk[8];
#pragma unroll
    for (int r = 0; r < 8; ++r) { tmax[r] = -3.0e38f; msk[r] = 0u; }

    const int nouter = (K + TILE - 1) / TILE;          // <= 4 (512 cols each)

    for (int t = 0; t < nouter; ++t) {
        float acc[8][8];
#pragma unroll
        for (int r = 0; r < 8; ++r)
#pragma unroll
            for (int j = 0; j < 8; ++j) acc[r][j] = 0.0f;

#pragma unroll 2
        for (int k4 = 0; k4 < 16; ++k4) {
            float4 rv[8];
#pragma unroll
            for (int r = 0; r < 8; ++r)
                rv[r] = x4[(size_t)rtok[r] * 16 + k4];
            const float4* cmk = cm + (size_t)k4 * NN + t * TILE + lane;
            float4 cv[8];
#pragma unroll
            for (int j = 0; j < 8; ++j)
                cv[j] = cmk[j * 64];                   // colp = t*512+j*64+lane
#pragma unroll
            for (int r = 0; r < 8; ++r)
#pragma unroll
                for (int j = 0; j < 8; ++j)
                    acc[r][j] = fmaf(rv[r].x, cv[j].x,
                                fmaf(rv[r].y, cv[j].y,
                                fmaf(rv[r].z, cv[j].z,
                                fmaf(rv[r].w, cv[j].w, acc[r][j]))));
        }

#pragma unroll
        for (int r = 0; r < 8; ++r)
#pragma unroll
            for (int j = 0; j < 8; ++j) {
                int colp = t * TILE + j * 64 + lane;
                float s = (colp < K) ? acc[r][j] : -1.0e30f;
                unsigned bit = 1u << ((t << 3) | j);
                if (s > tmax[r])       { tmax[r] = s; msk[r] = bit; }
                else if (s == tmax[r])  msk[r] |= bit;
            }
    }

    // ---- edge emission: per wave, per valid row ----
    int nvr = P - base - wid * 8;
    for (int r = 0; r < 8; ++r) {
        if (r >= nvr) break;
        float m = tmax[r];
#pragma unroll
        for (int off = 32; off; off >>= 1) m = fmaxf(m, __shfl_xor(m, off, 64));
        int src = rtok[r];
        float w  = expf(m * invn[b * NN + src]);
        float xv = x[(size_t)(b * NN + src) * CC + lane];
        unsigned long long bal = __ballot(tmax[r] == m && msk[r] != 0u);
        while (bal) {
            int sl = __ffsll(bal) - 1;
            bal &= bal - 1;
            unsigned mm = __shfl(msk[r], sl);
            while (mm) {
                int bit = __ffs(mm) - 1;
                mm &= mm - 1;
                int colp = ((bit >> 3) * TILE) + ((bit & 7) * 64) + sl;
                int dst = listK[b * NN + colp];
                atomicAdd(&A[(size_t)(b * NN + dst) * CC + lane], w * xv);
                if (lane == 0) atomicAdd(&S[b * NN + dst], w);
            }
        }
    }
}

// ---------------------------------------------------------------------------
// K4: out = (e*x + A) / (e + S).  A aliases d_out (in-place), float4.
// ---------------------------------------------------------------------------
__global__ __launch_bounds__(TPB) void k_finalize(const float* __restrict__ x,
                                                  const float* __restrict__ S,
                                                  float* __restrict__ out) {
    int i = blockIdx.x * TPB + threadIdx.x;
    int row = i >> 4;
    float inv = 1.0f / (E_CONST + S[row]);
    float4 xv = ((const float4*)x)[i];
    float4 av = ((float4*)out)[i];
    float4 o;
    o.x = (xv.x * E_CONST + av.x) * inv;
    o.y = (xv.y * E_CONST + av.y) * inv;
    o.z = (xv.z * E_CONST + av.z) * inv;
    o.w = (xv.w * E_CONST + av.w) * inv;
    ((float4*)out)[i] = o;
}

// ---------------------------------------------------------------------------
extern "C" void kernel_launch(void* const* d_in, const int* in_sizes, int n_in,
                              void* d_out, int out_size, void* d_ws, size_t ws_size,
                              hipStream_t stream) {
    const float* x    = (const float*)d_in[0];
    const float* keep = (const float*)d_in[2];
    float* out = (float*)d_out;

    // ws: invn 128KB | S 128KB | cnts 128B | listP 128KB | listK 128KB | colM 8MB
    char* ws = (char*)d_ws;
    float* invn = (float*)ws;
    float* S    = (float*)(ws + (128 << 10));
    int*   cntP = (int*)(ws + (256 << 10));
    int*   cntK = cntP + 16;
    int*   listP = (int*)(ws + (256 << 10) + 128);
    int*   listK = listP + BB * NN;
    float4* colM = (float4*)(ws + (1 << 20));

    k_pre<<<BB * NN / 4, TPB, 0, stream>>>(x, keep, invn, out, S,
                                           cntP, cntK, listP, listK);

    dim3 gp2(NN / TPB, BB);
    k_pre2<<<gp2, TPB, 0, stream>>>(x, invn, cntK, listK, colM);

    dim3 ga(NN / MROWS, BB);
    k_argmax_v2<<<ga, TPB, 0, stream>>>(x, colM, invn, cntP, cntK,
                                        listP, listK, S, out);

    k_finalize<<<(BB * NN * CC / 4) / TPB, TPB, 0, stream>>>(x, S, out);
}